// Round 13
// baseline (250.425 us; speedup 1.0000x reference)
//
#include <hip/hip_runtime.h>
#include <hip/hip_bf16.h>
#include <math.h>

// Problem constants
#define Bn 2
#define Sn 2048
#define Dn 1024
#define Hn 16
#define DKn 64
#define BHS (Bn * Hn * Sn)

using fragb  = __attribute__((ext_vector_type(8))) short;      // 8 bf16
using frag16 = __attribute__((ext_vector_type(8))) _Float16;   // 8 fp16
using f4     = __attribute__((ext_vector_type(4))) float;

__device__ __forceinline__ short f2bf(float f) {
    union { float f; unsigned u; } v; v.f = f;
    unsigned r = v.u + 0x7FFF + ((v.u >> 16) & 1);   // RNE
    return (short)(r >> 16);
}
__device__ __forceinline__ unsigned short f2h(float f) {
    _Float16 h = (_Float16)f;                         // RNE
    unsigned short s; __builtin_memcpy(&s, &h, 2); return s;
}

// async global->LDS, 16B per lane; LDS dest = wave-uniform base + lane*16
#define GLOAD(gptr, lptr)                                                     \
    __builtin_amdgcn_global_load_lds(                                         \
        (const __attribute__((address_space(1))) unsigned int*)(const void*)(gptr), \
        (__attribute__((address_space(3))) unsigned int*)(void*)(lptr), 16, 0, 0)

// ---------------- prep: fp32 -> fp16 casts (x4 vectorized) + bf16 mask row --
#define NX (Bn * Sn * Dn)      // 4M
#define NW (Dn * Dn)           // 1M
#define NF4 ((NX + 4 * NW) / 4)

__global__ __launch_bounds__(256) void prep(
    const float* __restrict__ x,  const float* __restrict__ Wq,
    const float* __restrict__ Wk, const float* __restrict__ Wv,
    const float* __restrict__ Wo, const int* __restrict__ mask,
    short* __restrict__ xh,
    short* __restrict__ Wqh, short* __restrict__ Wkh,
    short* __restrict__ Wvh, short* __restrict__ Woh,
    short* __restrict__ mfb)
{
    int i = blockIdx.x * 256 + threadIdx.x;
    if (i < NF4) {
        int e = i << 2;
        const float* src; short* dst; int j;
        if (e < NX)               { src = x;  dst = xh;  j = e; }
        else if (e < NX + NW)     { src = Wq; dst = Wqh; j = e - NX; }
        else if (e < NX + 2 * NW) { src = Wk; dst = Wkh; j = e - NX - NW; }
        else if (e < NX + 3 * NW) { src = Wv; dst = Wvh; j = e - NX - 2 * NW; }
        else                      { src = Wo; dst = Woh; j = e - NX - 3 * NW; }
        float4 v = *(const float4*)(src + j);
        ushort4 o;
        o.x = f2h(v.x); o.y = f2h(v.y); o.z = f2h(v.z); o.w = f2h(v.w);
        *(ushort4*)(dst + j) = o;
    } else {
        int j = (i - NF4) << 2;
        if (j < Bn * Sn) {
            int4 m = *(const int4*)(mask + j);
            ushort4 o;
            o.x = m.x ? 0x3F80 : 0; o.y = m.y ? 0x3F80 : 0;
            o.z = m.z ? 0x3F80 : 0; o.w = m.w ? 0x3F80 : 0;
            *(ushort4*)(mfb + j) = o;
        }
    }
}

// ---------------- QKV GEMM: fp16, R0 structure (BK=32, single buffer) -------
// Both-sides LDS XOR swizzle (conflicts 3.1M -> 0, time-neutral, kept).
__global__ __launch_bounds__(256) void gemm_qkv(
    const short* __restrict__ A,
    const short* __restrict__ W0, const float* __restrict__ b0,
    const short* __restrict__ W1, const float* __restrict__ b1,
    const short* __restrict__ W2, const float* __restrict__ b2,
    const int* __restrict__ mask,
    short* __restrict__ Qb, short* __restrict__ Kb, short* __restrict__ Vtb)
{
    __shared__ __align__(16) short As[128 * 32];
    __shared__ __align__(16) short Bs[128 * 32];

    const int tid  = threadIdx.x;
    const int wave = tid >> 6;
    const int lane = tid & 63;
    const int quad = lane >> 4;
    const int l16  = lane & 15;
    const int wm   = wave >> 1;
    const int wn   = wave & 1;

    const int m0   = blockIdx.y * 128;
    const int n0   = blockIdx.x * 128;
    const int widx = n0 >> 10;
    const int nl0  = n0 & 1023;

    const short* Wp   = widx == 0 ? W0 : (widx == 1 ? W1 : W2);
    const float* bias = widx == 0 ? b0 : (widx == 1 ? b1 : b2);

    f4 acc[4][4];
    #pragma unroll
    for (int i = 0; i < 4; i++)
        #pragma unroll
        for (int j = 0; j < 4; j++) {
            acc[i][j][0] = 0.f; acc[i][j][1] = 0.f;
            acc[i][j][2] = 0.f; acc[i][j][3] = 0.f;
        }

    const int K  = Dn;
    const int r0 = tid >> 2;                              // staged row 0..63
    const int r1 = (tid + 256) >> 2;                      // staged row 64..127
    const int sc = ((tid & 3) ^ ((tid >> 3) & 3)) * 8;    // pre-swizzled chunk
    const short* Ar0 = A  + (size_t)(m0  + r0) * K + sc;
    const short* Ar1 = A  + (size_t)(m0  + r1) * K + sc;
    const short* Br0 = Wp + (size_t)(nl0 + r0) * K + sc;
    const short* Br1 = Wp + (size_t)(nl0 + r1) * K + sc;

    const int cA = (quad ^ ((l16 >> 1) & 3)) * 8;         // swizzled read chunk

    for (int k0 = 0; k0 < K; k0 += 32) {
        __syncthreads();
        GLOAD(Ar0 + k0, &As[(wave * 64) * 8]);
        GLOAD(Ar1 + k0, &As[(256 + wave * 64) * 8]);
        GLOAD(Br0 + k0, &Bs[(wave * 64) * 8]);
        GLOAD(Br1 + k0, &Bs[(256 + wave * 64) * 8]);
        __syncthreads();

        frag16 a[4], b[4];
        #pragma unroll
        for (int mi = 0; mi < 4; mi++)
            a[mi] = *(const frag16*)&As[(wm * 64 + mi * 16 + l16) * 32 + cA];
        #pragma unroll
        for (int ni = 0; ni < 4; ni++)
            b[ni] = *(const frag16*)&Bs[(wn * 64 + ni * 16 + l16) * 32 + cA];
        #pragma unroll
        for (int mi = 0; mi < 4; mi++)
            #pragma unroll
            for (int ni = 0; ni < 4; ni++)
                acc[mi][ni] = __builtin_amdgcn_mfma_f32_16x16x32_f16(
                    a[mi], b[ni], acc[mi][ni], 0, 0, 0);
    }

    const float QSCALE = 0.125f * 1.44269504088896340736f;

    #pragma unroll
    for (int mi = 0; mi < 4; mi++) {
        #pragma unroll
        for (int ni = 0; ni < 4; ni++) {
            int nl = nl0 + wn * 64 + ni * 16 + l16;
            float bv = bias[nl];
            #pragma unroll
            for (int r = 0; r < 4; r++) {
                int m = m0 + wm * 64 + mi * 16 + quad * 4 + r;
                float v = acc[mi][ni][r] + bv;
                int b  = m >> 11, s = m & (Sn - 1);
                int h  = nl >> 6, dk = nl & 63;
                if (widx == 0)
                    Qb[((size_t)(b * Hn + h) * Sn + s) * DKn + dk] = f2bf(v * QSCALE);
                else if (widx == 1)
                    Kb[((size_t)(b * Hn + h) * Sn + s) * DKn + dk] = f2bf(v);
                else {
                    float mv = (float)mask[b * Sn + s];
                    Vtb[((size_t)(b * Hn + h) * DKn + dk) * Sn + s] = f2bf(v * mv);
                }
            }
        }
    }
}

// ---------------- Out GEMM: fp16, R0 structure (BM=64), + swizzle -----------
__global__ __launch_bounds__(256) void gemm_out(
    const short* __restrict__ A, const short* __restrict__ Wp,
    const float* __restrict__ bias, float* __restrict__ outf)
{
    __shared__ __align__(16) short As[64 * 32];
    __shared__ __align__(16) short Bs[128 * 32];

    const int tid  = threadIdx.x;
    const int wave = tid >> 6;
    const int lane = tid & 63;
    const int quad = lane >> 4;
    const int l16  = lane & 15;
    const int wm   = wave >> 1;
    const int wn   = wave & 1;

    const int m0 = blockIdx.y * 64;
    const int n0 = blockIdx.x * 128;

    f4 acc[2][4];
    #pragma unroll
    for (int i = 0; i < 2; i++)
        #pragma unroll
        for (int j = 0; j < 4; j++) {
            acc[i][j][0] = 0.f; acc[i][j][1] = 0.f;
            acc[i][j][2] = 0.f; acc[i][j][3] = 0.f;
        }

    const int K  = Dn;
    const int r0 = tid >> 2;
    const int r1 = (tid + 256) >> 2;
    const int sc = ((tid & 3) ^ ((tid >> 3) & 3)) * 8;
    const short* Ar0 = A  + (size_t)(m0 + r0) * K + sc;
    const short* Br0 = Wp + (size_t)(n0 + r0) * K + sc;
    const short* Br1 = Wp + (size_t)(n0 + r1) * K + sc;

    const int cA = (quad ^ ((l16 >> 1) & 3)) * 8;

    for (int k0 = 0; k0 < K; k0 += 32) {
        __syncthreads();
        GLOAD(Ar0 + k0, &As[(wave * 64) * 8]);
        GLOAD(Br0 + k0, &Bs[(wave * 64) * 8]);
        GLOAD(Br1 + k0, &Bs[(256 + wave * 64) * 8]);
        __syncthreads();

        frag16 a[2], b[4];
        #pragma unroll
        for (int mi = 0; mi < 2; mi++)
            a[mi] = *(const frag16*)&As[(wm * 32 + mi * 16 + l16) * 32 + cA];
        #pragma unroll
        for (int ni = 0; ni < 4; ni++)
            b[ni] = *(const frag16*)&Bs[(wn * 64 + ni * 16 + l16) * 32 + cA];
        #pragma unroll
        for (int mi = 0; mi < 2; mi++)
            #pragma unroll
            for (int ni = 0; ni < 4; ni++)
                acc[mi][ni] = __builtin_amdgcn_mfma_f32_16x16x32_f16(
                    a[mi], b[ni], acc[mi][ni], 0, 0, 0);
    }

    #pragma unroll
    for (int mi = 0; mi < 2; mi++) {
        #pragma unroll
        for (int ni = 0; ni < 4; ni++) {
            int nl = n0 + wn * 64 + ni * 16 + l16;
            float bv = bias[nl];
            #pragma unroll
            for (int r = 0; r < 4; r++) {
                int m = m0 + wm * 32 + mi * 16 + quad * 4 + r;
                outf[(size_t)m * Dn + nl] = acc[mi][ni][r] + bv;
            }
        }
    }
}

// ---------------- Flash attention: merged K, KVBLK=128, T14 reg-staging -----
// R13 delta (single change vs R12): K/V/mask staging converted from
// global_load_lds to T14 async-STAGE split (catalog: +17% attn, m214v27).
// Loads for round r+1 are issued into per-lane registers BEFORE compute(r)
// (they fly under the ~2000-cycle compute phase); after the readers' barrier
// they are ds_written to the IDENTICAL LDS addresses the old GLOADs used
// (same swizzle, same round order -> bit-identical numerics). The loads'
// only consumer (the ds_write block) sits after the whole compute phase, so
// the compiler's per-register waitcnt is already satisfied - unlike the
// barrier-drain that defeated every global_load_lds prefetch attempt.
// ds_write_b128 at lane*16B stride = 2-way bank access (free). +36 VGPR
// (68 -> ~105), no occupancy impact at 2 blocks/CU.
// + XCD-local heads (R10), KVBLK=128 (R12), T5 setprio (m191).
#define LP  72

__global__ __launch_bounds__(256) void attn_mfma(
    const short* __restrict__ Qb, const short* __restrict__ Kb,
    const short* __restrict__ Vtb, const short* __restrict__ mfb,
    short* __restrict__ Ch)
{
    __shared__ __align__(16) short Ks[2][64 * 64];
    __shared__ __align__(16) short Vs[2][64 * 64];
    __shared__ short Ps[4][32 * LP];
    __shared__ __align__(16) short mfs[128];

    const int tid  = threadIdx.x;
    const int wave = tid >> 6;
    const int lane = tid & 63;
    const int quad = lane >> 4;
    const int l16  = lane & 15;

    const int x   = blockIdx.x;                 // 512 blocks
    const int bhh = (x & 7) + ((x >> 7) << 3);  // 4 heads per XCD (R10 swizzle)
    const int qt  = (x >> 3) & 15;
    const int b   = bhh >> 4;
    const int h   = bhh & 15;

    fragb qf[2][2];
    #pragma unroll
    for (int w = 0; w < 2; w++) {
        int qrow = qt * 128 + wave * 32 + w * 16 + l16;
        const short* qptr = Qb + ((size_t)bhh * Sn + qrow) * DKn + quad * 8;
        qf[w][0] = *(const fragb*)(qptr);
        qf[w][1] = *(const fragb*)(qptr + 32);
    }

    f4 ctx[2][4];
    #pragma unroll
    for (int w = 0; w < 2; w++)
        #pragma unroll
        for (int dt = 0; dt < 4; dt++) {
            ctx[w][dt][0] = 0.f; ctx[w][dt][1] = 0.f;
            ctx[w][dt][2] = 0.f; ctx[w][dt][3] = 0.f;
        }
    f4 lacc[2];
    lacc[0][0] = 0.f; lacc[0][1] = 0.f; lacc[0][2] = 0.f; lacc[0][3] = 0.f;
    lacc[1] = lacc[0];

    const int lr = lane >> 3;
    const int sc = ((lane & 7) ^ lr) * 8;
    const short* Kg = Kb  + (size_t)bhh * Sn * DKn;
    const short* Vg = Vtb + (size_t)bhh * DKn * Sn;
    const short* mg = mfb + (size_t)b * Sn;

    const short* Ksrc = Kg + (size_t)(wave * 16 + lr) * DKn + sc;
    const short* Vsrc = Vg + (size_t)(wave * 16 + lr) * Sn + sc;

    // per-lane LDS write addresses (identical to old GLOAD dests: wave base
    // + lane*16B)
    short* dK0a = &Ks[0][(wave * 16) * 64 + lane * 8];
    short* dK0b = &Ks[0][(wave * 16 + 8) * 64 + lane * 8];
    short* dK1a = &Ks[1][(wave * 16) * 64 + lane * 8];
    short* dK1b = &Ks[1][(wave * 16 + 8) * 64 + lane * 8];
    short* dV0a = &Vs[0][(wave * 16) * 64 + lane * 8];
    short* dV0b = &Vs[0][(wave * 16 + 8) * 64 + lane * 8];
    short* dV1a = &Vs[1][(wave * 16) * 64 + lane * 8];
    short* dV1b = &Vs[1][(wave * 16 + 8) * 64 + lane * 8];

    const int c0 = ((quad ^ (l16 & 7)) * 8);

    uint4 rg[8];     // staged K/V for the next round (T14 reg buffer)
    uint4 mreg;

#define LOADREGS(r) do {                                                      \
    rg[0] = *(const uint4*)(Ksrc + (size_t)(2 * (r)) * 4096);                 \
    rg[1] = *(const uint4*)(Ksrc + (size_t)(2 * (r)) * 4096 + 8 * DKn);       \
    rg[2] = *(const uint4*)(Ksrc + (size_t)(2 * (r) + 1) * 4096);             \
    rg[3] = *(const uint4*)(Ksrc + (size_t)(2 * (r) + 1) * 4096 + 8 * DKn);   \
    rg[4] = *(const uint4*)(Vsrc + (size_t)(2 * (r)) * 64);                   \
    rg[5] = *(const uint4*)(Vsrc + (size_t)(2 * (r)) * 64 + 8 * Sn);          \
    rg[6] = *(const uint4*)(Vsrc + (size_t)(2 * (r) + 1) * 64);               \
    rg[7] = *(const uint4*)(Vsrc + (size_t)(2 * (r) + 1) * 64 + 8 * Sn);      \
    if (tid < 16) mreg = *(const uint4*)(mg + (r) * 128 + tid * 8);           \
} while (0)

#define WRITELDS() do {                                                       \
    *(uint4*)dK0a = rg[0];                                                    \
    *(uint4*)dK0b = rg[1];                                                    \
    *(uint4*)dK1a = rg[2];                                                    \
    *(uint4*)dK1b = rg[3];                                                    \
    *(uint4*)dV0a = rg[4];                                                    \
    *(uint4*)dV0b = rg[5];                                                    \
    *(uint4*)dV1a = rg[6];                                                    \
    *(uint4*)dV1b = rg[7];                                                    \
    if (tid < 16) *(uint4*)&mfs[tid * 8] = mreg;                              \
} while (0)

    LOADREGS(0);
    for (int r = 0; r < 16; r++) {
        __syncthreads();            // readers of previous round done
        WRITELDS();                 // vmcnt waits here are already satisfied
        __syncthreads();            // LDS ready for this round
        if (r < 15) LOADREGS(r + 1);  // fly under compute

        #pragma unroll
        for (int hs = 0; hs < 2; hs++) {
            #pragma unroll
            for (int t = 0; t < 4; t++) {
                fragb k0 = *(const fragb*)&Ks[hs][(t * 16 + l16) * 64 + c0];
                fragb k1 = *(const fragb*)&Ks[hs][(t * 16 + l16) * 64 + (c0 ^ 32)];
                #pragma unroll
                for (int w = 0; w < 2; w++) {
                    f4 a; a[0] = 0.f; a[1] = 0.f; a[2] = 0.f; a[3] = 0.f;
                    __builtin_amdgcn_s_setprio(1);
                    a = __builtin_amdgcn_mfma_f32_16x16x32_bf16(k0, qf[w][0], a, 0, 0, 0);
                    a = __builtin_amdgcn_mfma_f32_16x16x32_bf16(k1, qf[w][1], a, 0, 0, 0);
                    __builtin_amdgcn_s_setprio(0);
                    // raw v_exp_f32 (log2e folded into Q): 1 instr vs OCML's ~8
                    unsigned u0 = __float_as_uint(__builtin_amdgcn_exp2f(a[0]));
                    unsigned u1 = __float_as_uint(__builtin_amdgcn_exp2f(a[1]));
                    unsigned u2 = __float_as_uint(__builtin_amdgcn_exp2f(a[2]));
                    unsigned u3 = __float_as_uint(__builtin_amdgcn_exp2f(a[3]));
                    uint2 pw;
                    pw.x = __builtin_amdgcn_perm(u1, u0, 0x07060302u);
                    pw.y = __builtin_amdgcn_perm(u3, u2, 0x07060302u);
                    *(uint2*)&Ps[wave][(w * 16 + l16) * LP + 16 * t + quad * 4] = pw;
                }
            }

            fragb p[2][2];
            #pragma unroll
            for (int w = 0; w < 2; w++) {
                p[w][0] = *(const fragb*)&Ps[wave][(w * 16 + l16) * LP + quad * 8];
                p[w][1] = *(const fragb*)&Ps[wave][(w * 16 + l16) * LP + quad * 8 + 32];
            }
            fragb m0 = *(const fragb*)&mfs[hs * 64 + quad * 8];
            fragb m1 = *(const fragb*)&mfs[hs * 64 + quad * 8 + 32];
            __builtin_amdgcn_s_setprio(1);
            #pragma unroll
            for (int w = 0; w < 2; w++) {
                lacc[w] = __builtin_amdgcn_mfma_f32_16x16x32_bf16(p[w][0], m0, lacc[w], 0, 0, 0);
                lacc[w] = __builtin_amdgcn_mfma_f32_16x16x32_bf16(p[w][1], m1, lacc[w], 0, 0, 0);
            }
            #pragma unroll
            for (int dt = 0; dt < 4; dt++) {
                fragb v0 = *(const fragb*)&Vs[hs][(dt * 16 + l16) * 64 + c0];
                fragb v1 = *(const fragb*)&Vs[hs][(dt * 16 + l16) * 64 + (c0 ^ 32)];
                #pragma unroll
                for (int w = 0; w < 2; w++) {
                    ctx[w][dt] = __builtin_amdgcn_mfma_f32_16x16x32_bf16(p[w][0], v0, ctx[w][dt], 0, 0, 0);
                    ctx[w][dt] = __builtin_amdgcn_mfma_f32_16x16x32_bf16(p[w][1], v1, ctx[w][dt], 0, 0, 0);
                }
            }
            __builtin_amdgcn_s_setprio(0);
        }
    }

    // normalize in-register (lacc[w][r] = row's denom, same in all 16 lanes)
    #pragma unroll
    for (int w = 0; w < 2; w++)
        #pragma unroll
        for (int r = 0; r < 4; r++) {
            int row = qt * 128 + wave * 32 + w * 16 + quad * 4 + r;
            float inv = 1.f / lacc[w][r];
            #pragma unroll
            for (int dt = 0; dt < 4; dt++)
                Ch[((size_t)(b * Sn + row)) * Dn + h * DKn + dt * 16 + l16] =
                    f2h(ctx[w][dt][r] * inv);
        }
}

// ---------------- launch ----------------
extern "C" void kernel_launch(void* const* d_in, const int* in_sizes, int n_in,
                              void* d_out, int out_size, void* d_ws, size_t ws_size,
                              hipStream_t stream) {
    const float* x    = (const float*)d_in[0];
    const int*   mask = (const int*)d_in[1];
    const float* Wq   = (const float*)d_in[2];
    const float* bq   = (const float*)d_in[3];
    const float* Wk   = (const float*)d_in[4];
    const float* bk   = (const float*)d_in[5];
    const float* Wv   = (const float*)d_in[6];
    const float* bv   = (const float*)d_in[7];
    const float* Wo   = (const float*)d_in[8];
    const float* bo   = (const float*)d_in[9];
    float* out = (float*)d_out;

    char* ws = (char*)d_ws;
    const size_t MB = 1024u * 1024u;
    short* xh    = (short*)(ws + 0 * MB);    // 8 MB fp16 (dead after QKV)
    short* Wqh   = (short*)(ws + 8 * MB);
    short* Wkh   = (short*)(ws + 10 * MB);
    short* Wvh   = (short*)(ws + 12 * MB);
    short* Qb    = (short*)(ws + 16 * MB);
    short* Kb    = (short*)(ws + 24 * MB);
    short* Vtb   = (short*)(ws + 32 * MB);
    short* Woh   = (short*)(ws + 56 * MB);
    short* mfb   = (short*)(ws + 59 * MB);
    short* Ch    = (short*)(ws + 60 * MB);

    const int PRE = NF4 + (Bn * Sn) / 4;
    prep<<<(PRE + 255) / 256, 256, 0, stream>>>(
        x, Wq, Wk, Wv, Wo, mask, xh, Wqh, Wkh, Wvh, Woh, mfb);

    gemm_qkv<<<dim3(24, 32), 256, 0, stream>>>(
        xh, Wqh, bq, Wkh, bk, Wvh, bv, mask, Qb, Kb, Vtb);

    attn_mfma<<<dim3(Bn * Hn * (Sn / 128)), 256, 0, stream>>>(
        Qb, Kb, Vtb, mfb, Ch);

    gemm_out<<<dim3(8, 64), 256, 0, stream>>>(Ch, Woh, bo, out);
}

// Round 14
// 206.424 us; speedup vs baseline: 1.2132x; 1.2132x over previous
//
#include <hip/hip_runtime.h>
#include <hip/hip_bf16.h>
#include <math.h>

// Problem constants
#define Bn 2
#define Sn 2048
#define Dn 1024
#define Hn 16
#define DKn 64
#define BHS (Bn * Hn * Sn)

using fragb  = __attribute__((ext_vector_type(8))) short;      // 8 bf16
using frag16 = __attribute__((ext_vector_type(8))) _Float16;   // 8 fp16
using f4     = __attribute__((ext_vector_type(4))) float;

__device__ __forceinline__ short f2bf(float f) {
    union { float f; unsigned u; } v; v.f = f;
    unsigned r = v.u + 0x7FFF + ((v.u >> 16) & 1);   // RNE
    return (short)(r >> 16);
}
__device__ __forceinline__ unsigned short f2h(float f) {
    _Float16 h = (_Float16)f;                         // RNE
    unsigned short s; __builtin_memcpy(&s, &h, 2); return s;
}

// async global->LDS, 16B per lane; LDS dest = wave-uniform base + lane*16
#define GLOAD(gptr, lptr)                                                     \
    __builtin_amdgcn_global_load_lds(                                         \
        (const __attribute__((address_space(1))) unsigned int*)(const void*)(gptr), \
        (__attribute__((address_space(3))) unsigned int*)(void*)(lptr), 16, 0, 0)

// ---------------- prep: fp32 -> fp16 casts (x4 vectorized) + bf16 mask row --
#define NX (Bn * Sn * Dn)      // 4M
#define NW (Dn * Dn)           // 1M
#define NF4 ((NX + 4 * NW) / 4)

__global__ __launch_bounds__(256) void prep(
    const float* __restrict__ x,  const float* __restrict__ Wq,
    const float* __restrict__ Wk, const float* __restrict__ Wv,
    const float* __restrict__ Wo, const int* __restrict__ mask,
    short* __restrict__ xh,
    short* __restrict__ Wqh, short* __restrict__ Wkh,
    short* __restrict__ Wvh, short* __restrict__ Woh,
    short* __restrict__ mfb)
{
    int i = blockIdx.x * 256 + threadIdx.x;
    if (i < NF4) {
        int e = i << 2;
        const float* src; short* dst; int j;
        if (e < NX)               { src = x;  dst = xh;  j = e; }
        else if (e < NX + NW)     { src = Wq; dst = Wqh; j = e - NX; }
        else if (e < NX + 2 * NW) { src = Wk; dst = Wkh; j = e - NX - NW; }
        else if (e < NX + 3 * NW) { src = Wv; dst = Wvh; j = e - NX - 2 * NW; }
        else                      { src = Wo; dst = Woh; j = e - NX - 3 * NW; }
        float4 v = *(const float4*)(src + j);
        ushort4 o;
        o.x = f2h(v.x); o.y = f2h(v.y); o.z = f2h(v.z); o.w = f2h(v.w);
        *(ushort4*)(dst + j) = o;
    } else {
        int j = (i - NF4) << 2;
        if (j < Bn * Sn) {
            int4 m = *(const int4*)(mask + j);
            ushort4 o;
            o.x = m.x ? 0x3F80 : 0; o.y = m.y ? 0x3F80 : 0;
            o.z = m.z ? 0x3F80 : 0; o.w = m.w ? 0x3F80 : 0;
            *(ushort4*)(mfb + j) = o;
        }
    }
}

// ---------------- QKV GEMM: fp16, R0 structure (BK=32, single buffer) -------
// Both-sides LDS XOR swizzle (conflicts 3.1M -> 0, time-neutral, kept).
__global__ __launch_bounds__(256) void gemm_qkv(
    const short* __restrict__ A,
    const short* __restrict__ W0, const float* __restrict__ b0,
    const short* __restrict__ W1, const float* __restrict__ b1,
    const short* __restrict__ W2, const float* __restrict__ b2,
    const int* __restrict__ mask,
    short* __restrict__ Qb, short* __restrict__ Kb, short* __restrict__ Vtb)
{
    __shared__ __align__(16) short As[128 * 32];
    __shared__ __align__(16) short Bs[128 * 32];

    const int tid  = threadIdx.x;
    const int wave = tid >> 6;
    const int lane = tid & 63;
    const int quad = lane >> 4;
    const int l16  = lane & 15;
    const int wm   = wave >> 1;
    const int wn   = wave & 1;

    const int m0   = blockIdx.y * 128;
    const int n0   = blockIdx.x * 128;
    const int widx = n0 >> 10;
    const int nl0  = n0 & 1023;

    const short* Wp   = widx == 0 ? W0 : (widx == 1 ? W1 : W2);
    const float* bias = widx == 0 ? b0 : (widx == 1 ? b1 : b2);

    f4 acc[4][4];
    #pragma unroll
    for (int i = 0; i < 4; i++)
        #pragma unroll
        for (int j = 0; j < 4; j++) {
            acc[i][j][0] = 0.f; acc[i][j][1] = 0.f;
            acc[i][j][2] = 0.f; acc[i][j][3] = 0.f;
        }

    const int K  = Dn;
    const int r0 = tid >> 2;                              // staged row 0..63
    const int r1 = (tid + 256) >> 2;                      // staged row 64..127
    const int sc = ((tid & 3) ^ ((tid >> 3) & 3)) * 8;    // pre-swizzled chunk
    const short* Ar0 = A  + (size_t)(m0  + r0) * K + sc;
    const short* Ar1 = A  + (size_t)(m0  + r1) * K + sc;
    const short* Br0 = Wp + (size_t)(nl0 + r0) * K + sc;
    const short* Br1 = Wp + (size_t)(nl0 + r1) * K + sc;

    const int cA = (quad ^ ((l16 >> 1) & 3)) * 8;         // swizzled read chunk

    for (int k0 = 0; k0 < K; k0 += 32) {
        __syncthreads();
        GLOAD(Ar0 + k0, &As[(wave * 64) * 8]);
        GLOAD(Ar1 + k0, &As[(256 + wave * 64) * 8]);
        GLOAD(Br0 + k0, &Bs[(wave * 64) * 8]);
        GLOAD(Br1 + k0, &Bs[(256 + wave * 64) * 8]);
        __syncthreads();

        frag16 a[4], b[4];
        #pragma unroll
        for (int mi = 0; mi < 4; mi++)
            a[mi] = *(const frag16*)&As[(wm * 64 + mi * 16 + l16) * 32 + cA];
        #pragma unroll
        for (int ni = 0; ni < 4; ni++)
            b[ni] = *(const frag16*)&Bs[(wn * 64 + ni * 16 + l16) * 32 + cA];
        #pragma unroll
        for (int mi = 0; mi < 4; mi++)
            #pragma unroll
            for (int ni = 0; ni < 4; ni++)
                acc[mi][ni] = __builtin_amdgcn_mfma_f32_16x16x32_f16(
                    a[mi], b[ni], acc[mi][ni], 0, 0, 0);
    }

    const float QSCALE = 0.125f * 1.44269504088896340736f;

    #pragma unroll
    for (int mi = 0; mi < 4; mi++) {
        #pragma unroll
        for (int ni = 0; ni < 4; ni++) {
            int nl = nl0 + wn * 64 + ni * 16 + l16;
            float bv = bias[nl];
            #pragma unroll
            for (int r = 0; r < 4; r++) {
                int m = m0 + wm * 64 + mi * 16 + quad * 4 + r;
                float v = acc[mi][ni][r] + bv;
                int b  = m >> 11, s = m & (Sn - 1);
                int h  = nl >> 6, dk = nl & 63;
                if (widx == 0)
                    Qb[((size_t)(b * Hn + h) * Sn + s) * DKn + dk] = f2bf(v * QSCALE);
                else if (widx == 1)
                    Kb[((size_t)(b * Hn + h) * Sn + s) * DKn + dk] = f2bf(v);
                else {
                    float mv = (float)mask[b * Sn + s];
                    Vtb[((size_t)(b * Hn + h) * DKn + dk) * Sn + s] = f2bf(v * mv);
                }
            }
        }
    }
}

// ---------------- Out GEMM: fp16, R0 structure (BM=64), + swizzle -----------
__global__ __launch_bounds__(256) void gemm_out(
    const short* __restrict__ A, const short* __restrict__ Wp,
    const float* __restrict__ bias, float* __restrict__ outf)
{
    __shared__ __align__(16) short As[64 * 32];
    __shared__ __align__(16) short Bs[128 * 32];

    const int tid  = threadIdx.x;
    const int wave = tid >> 6;
    const int lane = tid & 63;
    const int quad = lane >> 4;
    const int l16  = lane & 15;
    const int wm   = wave >> 1;
    const int wn   = wave & 1;

    const int m0 = blockIdx.y * 64;
    const int n0 = blockIdx.x * 128;

    f4 acc[2][4];
    #pragma unroll
    for (int i = 0; i < 2; i++)
        #pragma unroll
        for (int j = 0; j < 4; j++) {
            acc[i][j][0] = 0.f; acc[i][j][1] = 0.f;
            acc[i][j][2] = 0.f; acc[i][j][3] = 0.f;
        }

    const int K  = Dn;
    const int r0 = tid >> 2;
    const int r1 = (tid + 256) >> 2;
    const int sc = ((tid & 3) ^ ((tid >> 3) & 3)) * 8;
    const short* Ar0 = A  + (size_t)(m0 + r0) * K + sc;
    const short* Br0 = Wp + (size_t)(n0 + r0) * K + sc;
    const short* Br1 = Wp + (size_t)(n0 + r1) * K + sc;

    const int cA = (quad ^ ((l16 >> 1) & 3)) * 8;

    for (int k0 = 0; k0 < K; k0 += 32) {
        __syncthreads();
        GLOAD(Ar0 + k0, &As[(wave * 64) * 8]);
        GLOAD(Br0 + k0, &Bs[(wave * 64) * 8]);
        GLOAD(Br1 + k0, &Bs[(256 + wave * 64) * 8]);
        __syncthreads();

        frag16 a[2], b[4];
        #pragma unroll
        for (int mi = 0; mi < 2; mi++)
            a[mi] = *(const frag16*)&As[(wm * 32 + mi * 16 + l16) * 32 + cA];
        #pragma unroll
        for (int ni = 0; ni < 4; ni++)
            b[ni] = *(const frag16*)&Bs[(wn * 64 + ni * 16 + l16) * 32 + cA];
        #pragma unroll
        for (int mi = 0; mi < 2; mi++)
            #pragma unroll
            for (int ni = 0; ni < 4; ni++)
                acc[mi][ni] = __builtin_amdgcn_mfma_f32_16x16x32_f16(
                    a[mi], b[ni], acc[mi][ni], 0, 0, 0);
    }

    #pragma unroll
    for (int mi = 0; mi < 2; mi++) {
        #pragma unroll
        for (int ni = 0; ni < 4; ni++) {
            int nl = n0 + wn * 64 + ni * 16 + l16;
            float bv = bias[nl];
            #pragma unroll
            for (int r = 0; r < 4; r++) {
                int m = m0 + wm * 32 + mi * 16 + quad * 4 + r;
                outf[(size_t)m * Dn + nl] = acc[mi][ni][r] + bv;
            }
        }
    }
}

// ---------------- Flash attention: merged K, dbuf GLOAD prefetch ------------
// R14 delta (vs R12; R13's reg-staging reverted - it spilled to scratch,
// WRITE_SIZE 8->118 MB): double-buffered global_load_lds prefetch with
// STATIC buffers Ks[0]/Ks[1] (unrolled x2, no runtime LDS indexing). Per
// iteration: stage tile kt+1 into buffer B, compute buffer A (~1000-2000
// cy, >> L2-hit latency ~200-500 cy), barrier (vmcnt drain already
// satisfied), stage kt+2 into A, compute B, barrier. This is the regime
// where prefetch-under-compute works: compute >> latency (unlike qkv R1/R6
// where compute ~400 cy < latency and the drain stayed exposed). In-flight
// data lives in the DMA queue, not VGPRs -> no spill. Same per-tile
// addresses/swizzle as R10/R12, sequential kt order -> identical numerics.
// + XCD-local heads (R10), T5 setprio (m191).
#define LP  72

__global__ __launch_bounds__(256) void attn_mfma(
    const short* __restrict__ Qb, const short* __restrict__ Kb,
    const short* __restrict__ Vtb, const short* __restrict__ mfb,
    short* __restrict__ Ch)
{
    __shared__ __align__(16) short Ks[2][64 * 64];
    __shared__ __align__(16) short Vs[2][64 * 64];
    __shared__ short Ps[4][32 * LP];
    __shared__ __align__(16) short mfs[2][64];

    const int tid  = threadIdx.x;
    const int wave = tid >> 6;
    const int lane = tid & 63;
    const int quad = lane >> 4;
    const int l16  = lane & 15;

    const int x   = blockIdx.x;                 // 512 blocks
    const int bhh = (x & 7) + ((x >> 7) << 3);  // 4 heads per XCD (R10 swizzle)
    const int qt  = (x >> 3) & 15;
    const int b   = bhh >> 4;
    const int h   = bhh & 15;

    fragb qf[2][2];
    #pragma unroll
    for (int w = 0; w < 2; w++) {
        int qrow = qt * 128 + wave * 32 + w * 16 + l16;
        const short* qptr = Qb + ((size_t)bhh * Sn + qrow) * DKn + quad * 8;
        qf[w][0] = *(const fragb*)(qptr);
        qf[w][1] = *(const fragb*)(qptr + 32);
    }

    f4 ctx[2][4];
    #pragma unroll
    for (int w = 0; w < 2; w++)
        #pragma unroll
        for (int dt = 0; dt < 4; dt++) {
            ctx[w][dt][0] = 0.f; ctx[w][dt][1] = 0.f;
            ctx[w][dt][2] = 0.f; ctx[w][dt][3] = 0.f;
        }
    f4 lacc[2];
    lacc[0][0] = 0.f; lacc[0][1] = 0.f; lacc[0][2] = 0.f; lacc[0][3] = 0.f;
    lacc[1] = lacc[0];

    const int lr = lane >> 3;
    const int sc = ((lane & 7) ^ lr) * 8;
    const short* Kg = Kb  + (size_t)bhh * Sn * DKn;
    const short* Vg = Vtb + (size_t)bhh * DKn * Sn;
    const short* mg = mfb + (size_t)b * Sn;

    const short* Ksrc = Kg + (size_t)(wave * 16 + lr) * DKn + sc;
    const short* Vsrc = Vg + (size_t)(wave * 16 + lr) * Sn + sc;

    const int c0 = ((quad ^ (l16 & 7)) * 8);

#define STAGE_T(bi, kt) do {                                                  \
    GLOAD(Ksrc + (size_t)(kt) * 4096,           &Ks[bi][(wave * 16) * 64]);   \
    GLOAD(Ksrc + (size_t)(kt) * 4096 + 8 * DKn, &Ks[bi][(wave * 16 + 8) * 64]); \
    GLOAD(Vsrc + (size_t)(kt) * 64,             &Vs[bi][(wave * 16) * 64]);   \
    GLOAD(Vsrc + (size_t)(kt) * 64 + 8 * Sn,    &Vs[bi][(wave * 16 + 8) * 64]); \
    if (tid < 8)                                                              \
        *(uint4*)&mfs[bi][tid * 8] = *(const uint4*)(mg + (kt) * 64 + tid * 8); \
} while (0)

#define COMPUTE_T(bi) do {                                                    \
    _Pragma("unroll")                                                         \
    for (int t = 0; t < 4; t++) {                                             \
        fragb k0 = *(const fragb*)&Ks[bi][(t * 16 + l16) * 64 + c0];          \
        fragb k1 = *(const fragb*)&Ks[bi][(t * 16 + l16) * 64 + (c0 ^ 32)];   \
        _Pragma("unroll")                                                     \
        for (int w = 0; w < 2; w++) {                                         \
            f4 a; a[0] = 0.f; a[1] = 0.f; a[2] = 0.f; a[3] = 0.f;             \
            __builtin_amdgcn_s_setprio(1);                                    \
            a = __builtin_amdgcn_mfma_f32_16x16x32_bf16(k0, qf[w][0], a, 0, 0, 0); \
            a = __builtin_amdgcn_mfma_f32_16x16x32_bf16(k1, qf[w][1], a, 0, 0, 0); \
            __builtin_amdgcn_s_setprio(0);                                    \
            unsigned u0 = __float_as_uint(__builtin_amdgcn_exp2f(a[0]));      \
            unsigned u1 = __float_as_uint(__builtin_amdgcn_exp2f(a[1]));      \
            unsigned u2 = __float_as_uint(__builtin_amdgcn_exp2f(a[2]));      \
            unsigned u3 = __float_as_uint(__builtin_amdgcn_exp2f(a[3]));      \
            uint2 pw;                                                         \
            pw.x = __builtin_amdgcn_perm(u1, u0, 0x07060302u);                \
            pw.y = __builtin_amdgcn_perm(u3, u2, 0x07060302u);                \
            *(uint2*)&Ps[wave][(w * 16 + l16) * LP + 16 * t + quad * 4] = pw; \
        }                                                                     \
    }                                                                         \
    fragb p[2][2];                                                            \
    _Pragma("unroll")                                                         \
    for (int w = 0; w < 2; w++) {                                             \
        p[w][0] = *(const fragb*)&Ps[wave][(w * 16 + l16) * LP + quad * 8];   \
        p[w][1] = *(const fragb*)&Ps[wave][(w * 16 + l16) * LP + quad * 8 + 32]; \
    }                                                                         \
    fragb m0 = *(const fragb*)&mfs[bi][quad * 8];                             \
    fragb m1 = *(const fragb*)&mfs[bi][quad * 8 + 32];                        \
    __builtin_amdgcn_s_setprio(1);                                            \
    _Pragma("unroll")                                                         \
    for (int w = 0; w < 2; w++) {                                             \
        lacc[w] = __builtin_amdgcn_mfma_f32_16x16x32_bf16(p[w][0], m0, lacc[w], 0, 0, 0); \
        lacc[w] = __builtin_amdgcn_mfma_f32_16x16x32_bf16(p[w][1], m1, lacc[w], 0, 0, 0); \
    }                                                                         \
    _Pragma("unroll")                                                         \
    for (int dt = 0; dt < 4; dt++) {                                          \
        fragb v0 = *(const fragb*)&Vs[bi][(dt * 16 + l16) * 64 + c0];         \
        fragb v1 = *(const fragb*)&Vs[bi][(dt * 16 + l16) * 64 + (c0 ^ 32)];  \
        _Pragma("unroll")                                                     \
        for (int w = 0; w < 2; w++) {                                         \
            ctx[w][dt] = __builtin_amdgcn_mfma_f32_16x16x32_bf16(p[w][0], v0, ctx[w][dt], 0, 0, 0); \
            ctx[w][dt] = __builtin_amdgcn_mfma_f32_16x16x32_bf16(p[w][1], v1, ctx[w][dt], 0, 0, 0); \
        }                                                                     \
    }                                                                         \
    __builtin_amdgcn_s_setprio(0);                                            \
} while (0)

    STAGE_T(0, 0);
    __syncthreads();                      // tile 0 landed
    for (int kt = 0; kt < 32; kt += 2) {
        STAGE_T(1, kt + 1);               // prefetch flies under compute
        COMPUTE_T(0);
        __syncthreads();                  // tile kt+1 landed; readers of buf0 done
        if (kt + 2 < 32) STAGE_T(0, kt + 2);
        COMPUTE_T(1);
        __syncthreads();                  // tile kt+2 landed; readers of buf1 done
    }

    // normalize in-register (lacc[w][r] = row's denom, same in all 16 lanes)
    #pragma unroll
    for (int w = 0; w < 2; w++)
        #pragma unroll
        for (int r = 0; r < 4; r++) {
            int row = qt * 128 + wave * 32 + w * 16 + quad * 4 + r;
            float inv = 1.f / lacc[w][r];
            #pragma unroll
            for (int dt = 0; dt < 4; dt++)
                Ch[((size_t)(b * Sn + row)) * Dn + h * DKn + dt * 16 + l16] =
                    f2h(ctx[w][dt][r] * inv);
        }
}

// ---------------- launch ----------------
extern "C" void kernel_launch(void* const* d_in, const int* in_sizes, int n_in,
                              void* d_out, int out_size, void* d_ws, size_t ws_size,
                              hipStream_t stream) {
    const float* x    = (const float*)d_in[0];
    const int*   mask = (const int*)d_in[1];
    const float* Wq   = (const float*)d_in[2];
    const float* bq   = (const float*)d_in[3];
    const float* Wk   = (const float*)d_in[4];
    const float* bk   = (const float*)d_in[5];
    const float* Wv   = (const float*)d_in[6];
    const float* bv   = (const float*)d_in[7];
    const float* Wo   = (const float*)d_in[8];
    const float* bo   = (const float*)d_in[9];
    float* out = (float*)d_out;

    char* ws = (char*)d_ws;
    const size_t MB = 1024u * 1024u;
    short* xh    = (short*)(ws + 0 * MB);    // 8 MB fp16 (dead after QKV)
    short* Wqh   = (short*)(ws + 8 * MB);
    short* Wkh   = (short*)(ws + 10 * MB);
    short* Wvh   = (short*)(ws + 12 * MB);
    short* Qb    = (short*)(ws + 16 * MB);
    short* Kb    = (short*)(ws + 24 * MB);
    short* Vtb   = (short*)(ws + 32 * MB);
    short* Woh   = (short*)(ws + 56 * MB);
    short* mfb   = (short*)(ws + 59 * MB);
    short* Ch    = (short*)(ws + 60 * MB);

    const int PRE = NF4 + (Bn * Sn) / 4;
    prep<<<(PRE + 255) / 256, 256, 0, stream>>>(
        x, Wq, Wk, Wv, Wo, mask, xh, Wqh, Wkh, Wvh, Woh, mfb);

    gemm_qkv<<<dim3(24, 32), 256, 0, stream>>>(
        xh, Wqh, bq, Wkh, bk, Wvh, bv, mask, Qb, Kb, Vtb);

    attn_mfma<<<dim3(Bn * Hn * (Sn / 128)), 256, 0, stream>>>(
        Qb, Kb, Vtb, mfb, Ch);

    gemm_out<<<dim3(8, 64), 256, 0, stream>>>(Ch, Woh, bo, out);
}

// Round 15
// 201.634 us; speedup vs baseline: 1.2420x; 1.0238x over previous
//
#include <hip/hip_runtime.h>
#include <hip/hip_bf16.h>
#include <math.h>

// Problem constants
#define Bn 2
#define Sn 2048
#define Dn 1024
#define Hn 16
#define DKn 64
#define BHS (Bn * Hn * Sn)

using fragb  = __attribute__((ext_vector_type(8))) short;      // 8 bf16
using frag16 = __attribute__((ext_vector_type(8))) _Float16;   // 8 fp16
using f4     = __attribute__((ext_vector_type(4))) float;

__device__ __forceinline__ short f2bf(float f) {
    union { float f; unsigned u; } v; v.f = f;
    unsigned r = v.u + 0x7FFF + ((v.u >> 16) & 1);   // RNE
    return (short)(r >> 16);
}
__device__ __forceinline__ unsigned short f2h(float f) {
    _Float16 h = (_Float16)f;                         // RNE
    unsigned short s; __builtin_memcpy(&s, &h, 2); return s;
}

// async global->LDS, 16B per lane; LDS dest = wave-uniform base + lane*16
#define GLOAD(gptr, lptr)                                                     \
    __builtin_amdgcn_global_load_lds(                                         \
        (const __attribute__((address_space(1))) unsigned int*)(const void*)(gptr), \
        (__attribute__((address_space(3))) unsigned int*)(void*)(lptr), 16, 0, 0)

// ---------------- prep: fp32 -> fp16 casts (x4 vectorized) + bf16 mask row --
#define NX (Bn * Sn * Dn)      // 4M
#define NW (Dn * Dn)           // 1M
#define NF4 ((NX + 4 * NW) / 4)

__global__ __launch_bounds__(256) void prep(
    const float* __restrict__ x,  const float* __restrict__ Wq,
    const float* __restrict__ Wk, const float* __restrict__ Wv,
    const float* __restrict__ Wo, const int* __restrict__ mask,
    short* __restrict__ xh,
    short* __restrict__ Wqh, short* __restrict__ Wkh,
    short* __restrict__ Wvh, short* __restrict__ Woh,
    short* __restrict__ mfb)
{
    int i = blockIdx.x * 256 + threadIdx.x;
    if (i < NF4) {
        int e = i << 2;
        const float* src; short* dst; int j;
        if (e < NX)               { src = x;  dst = xh;  j = e; }
        else if (e < NX + NW)     { src = Wq; dst = Wqh; j = e - NX; }
        else if (e < NX + 2 * NW) { src = Wk; dst = Wkh; j = e - NX - NW; }
        else if (e < NX + 3 * NW) { src = Wv; dst = Wvh; j = e - NX - 2 * NW; }
        else                      { src = Wo; dst = Woh; j = e - NX - 3 * NW; }
        float4 v = *(const float4*)(src + j);
        ushort4 o;
        o.x = f2h(v.x); o.y = f2h(v.y); o.z = f2h(v.z); o.w = f2h(v.w);
        *(ushort4*)(dst + j) = o;
    } else {
        int j = (i - NF4) << 2;
        if (j < Bn * Sn) {
            int4 m = *(const int4*)(mask + j);
            ushort4 o;
            o.x = m.x ? 0x3F80 : 0; o.y = m.y ? 0x3F80 : 0;
            o.z = m.z ? 0x3F80 : 0; o.w = m.w ? 0x3F80 : 0;
            *(ushort4*)(mfb + j) = o;
        }
    }
}

// ---------------- QKV GEMM: fp16, R0 structure (BK=32, single buffer) -------
// Both-sides LDS XOR swizzle (conflicts 3.1M -> 0, time-neutral, kept).
__global__ __launch_bounds__(256) void gemm_qkv(
    const short* __restrict__ A,
    const short* __restrict__ W0, const float* __restrict__ b0,
    const short* __restrict__ W1, const float* __restrict__ b1,
    const short* __restrict__ W2, const float* __restrict__ b2,
    const int* __restrict__ mask,
    short* __restrict__ Qb, short* __restrict__ Kb, short* __restrict__ Vtb)
{
    __shared__ __align__(16) short As[128 * 32];
    __shared__ __align__(16) short Bs[128 * 32];

    const int tid  = threadIdx.x;
    const int wave = tid >> 6;
    const int lane = tid & 63;
    const int quad = lane >> 4;
    const int l16  = lane & 15;
    const int wm   = wave >> 1;
    const int wn   = wave & 1;

    const int m0   = blockIdx.y * 128;
    const int n0   = blockIdx.x * 128;
    const int widx = n0 >> 10;
    const int nl0  = n0 & 1023;

    const short* Wp   = widx == 0 ? W0 : (widx == 1 ? W1 : W2);
    const float* bias = widx == 0 ? b0 : (widx == 1 ? b1 : b2);

    f4 acc[4][4];
    #pragma unroll
    for (int i = 0; i < 4; i++)
        #pragma unroll
        for (int j = 0; j < 4; j++) {
            acc[i][j][0] = 0.f; acc[i][j][1] = 0.f;
            acc[i][j][2] = 0.f; acc[i][j][3] = 0.f;
        }

    const int K  = Dn;
    const int r0 = tid >> 2;                              // staged row 0..63
    const int r1 = (tid + 256) >> 2;                      // staged row 64..127
    const int sc = ((tid & 3) ^ ((tid >> 3) & 3)) * 8;    // pre-swizzled chunk
    const short* Ar0 = A  + (size_t)(m0  + r0) * K + sc;
    const short* Ar1 = A  + (size_t)(m0  + r1) * K + sc;
    const short* Br0 = Wp + (size_t)(nl0 + r0) * K + sc;
    const short* Br1 = Wp + (size_t)(nl0 + r1) * K + sc;

    const int cA = (quad ^ ((l16 >> 1) & 3)) * 8;         // swizzled read chunk

    for (int k0 = 0; k0 < K; k0 += 32) {
        __syncthreads();
        GLOAD(Ar0 + k0, &As[(wave * 64) * 8]);
        GLOAD(Ar1 + k0, &As[(256 + wave * 64) * 8]);
        GLOAD(Br0 + k0, &Bs[(wave * 64) * 8]);
        GLOAD(Br1 + k0, &Bs[(256 + wave * 64) * 8]);
        __syncthreads();

        frag16 a[4], b[4];
        #pragma unroll
        for (int mi = 0; mi < 4; mi++)
            a[mi] = *(const frag16*)&As[(wm * 64 + mi * 16 + l16) * 32 + cA];
        #pragma unroll
        for (int ni = 0; ni < 4; ni++)
            b[ni] = *(const frag16*)&Bs[(wn * 64 + ni * 16 + l16) * 32 + cA];
        #pragma unroll
        for (int mi = 0; mi < 4; mi++)
            #pragma unroll
            for (int ni = 0; ni < 4; ni++)
                acc[mi][ni] = __builtin_amdgcn_mfma_f32_16x16x32_f16(
                    a[mi], b[ni], acc[mi][ni], 0, 0, 0);
    }

    const float QSCALE = 0.125f * 1.44269504088896340736f;

    #pragma unroll
    for (int mi = 0; mi < 4; mi++) {
        #pragma unroll
        for (int ni = 0; ni < 4; ni++) {
            int nl = nl0 + wn * 64 + ni * 16 + l16;
            float bv = bias[nl];
            #pragma unroll
            for (int r = 0; r < 4; r++) {
                int m = m0 + wm * 64 + mi * 16 + quad * 4 + r;
                float v = acc[mi][ni][r] + bv;
                int b  = m >> 11, s = m & (Sn - 1);
                int h  = nl >> 6, dk = nl & 63;
                if (widx == 0)
                    Qb[((size_t)(b * Hn + h) * Sn + s) * DKn + dk] = f2bf(v * QSCALE);
                else if (widx == 1)
                    Kb[((size_t)(b * Hn + h) * Sn + s) * DKn + dk] = f2bf(v);
                else {
                    float mv = (float)mask[b * Sn + s];
                    Vtb[((size_t)(b * Hn + h) * DKn + dk) * Sn + s] = f2bf(v * mv);
                }
            }
        }
    }
}

// ---------------- Out GEMM: fp16, R0 structure (BM=64), + swizzle -----------
__global__ __launch_bounds__(256) void gemm_out(
    const short* __restrict__ A, const short* __restrict__ Wp,
    const float* __restrict__ bias, float* __restrict__ outf)
{
    __shared__ __align__(16) short As[64 * 32];
    __shared__ __align__(16) short Bs[128 * 32];

    const int tid  = threadIdx.x;
    const int wave = tid >> 6;
    const int lane = tid & 63;
    const int quad = lane >> 4;
    const int l16  = lane & 15;
    const int wm   = wave >> 1;
    const int wn   = wave & 1;

    const int m0 = blockIdx.y * 64;
    const int n0 = blockIdx.x * 128;

    f4 acc[2][4];
    #pragma unroll
    for (int i = 0; i < 2; i++)
        #pragma unroll
        for (int j = 0; j < 4; j++) {
            acc[i][j][0] = 0.f; acc[i][j][1] = 0.f;
            acc[i][j][2] = 0.f; acc[i][j][3] = 0.f;
        }

    const int K  = Dn;
    const int r0 = tid >> 2;
    const int r1 = (tid + 256) >> 2;
    const int sc = ((tid & 3) ^ ((tid >> 3) & 3)) * 8;
    const short* Ar0 = A  + (size_t)(m0 + r0) * K + sc;
    const short* Br0 = Wp + (size_t)(n0 + r0) * K + sc;
    const short* Br1 = Wp + (size_t)(n0 + r1) * K + sc;

    const int cA = (quad ^ ((l16 >> 1) & 3)) * 8;

    for (int k0 = 0; k0 < K; k0 += 32) {
        __syncthreads();
        GLOAD(Ar0 + k0, &As[(wave * 64) * 8]);
        GLOAD(Br0 + k0, &Bs[(wave * 64) * 8]);
        GLOAD(Br1 + k0, &Bs[(256 + wave * 64) * 8]);
        __syncthreads();

        frag16 a[2], b[4];
        #pragma unroll
        for (int mi = 0; mi < 2; mi++)
            a[mi] = *(const frag16*)&As[(wm * 32 + mi * 16 + l16) * 32 + cA];
        #pragma unroll
        for (int ni = 0; ni < 4; ni++)
            b[ni] = *(const frag16*)&Bs[(wn * 64 + ni * 16 + l16) * 32 + cA];
        #pragma unroll
        for (int mi = 0; mi < 2; mi++)
            #pragma unroll
            for (int ni = 0; ni < 4; ni++)
                acc[mi][ni] = __builtin_amdgcn_mfma_f32_16x16x32_f16(
                    a[mi], b[ni], acc[mi][ni], 0, 0, 0);
    }

    #pragma unroll
    for (int mi = 0; mi < 2; mi++) {
        #pragma unroll
        for (int ni = 0; ni < 4; ni++) {
            int nl = n0 + wn * 64 + ni * 16 + l16;
            float bv = bias[nl];
            #pragma unroll
            for (int r = 0; r < 4; r++) {
                int m = m0 + wm * 32 + mi * 16 + quad * 4 + r;
                outf[(size_t)m * Dn + nl] = acc[mi][ni][r] + bv;
            }
        }
    }
}

// ---------------- Flash attention: merged K, KVBLK=128, 8-WAVE blocks -------
// R15 delta (single change vs R12): same 128-row Q-tile x 128-key round,
// same staging volume and barrier schedule, but decomposed over 8 waves
// (512 threads) instead of 4. Per-wave: 16 Q-rows (qf/ctx/lacc halve),
// 4 GLOADs (wave>>2 selects which 64-key tile, wave&3 which 16-row slab).
// Mechanism: R11 (more blocks) and R14 (prefetch) both null -> residual
// idle is the per-wave serial QK^T->exp->Ps->PV chain with only 2 waves/
// SIMD to interleave. This doubles waves/SIMD (2->4) at IDENTICAL block
// arithmetic intensity (R11's failure mode avoided by construction). One
// wave owns each output row with the same kt order -> identical numerics.
// + XCD-local heads (R10), KVBLK=128 (R12), T5 setprio (m191).
#define LP  72

__global__ __launch_bounds__(512) void attn_mfma(
    const short* __restrict__ Qb, const short* __restrict__ Kb,
    const short* __restrict__ Vtb, const short* __restrict__ mfb,
    short* __restrict__ Ch)
{
    __shared__ __align__(16) short Ks[2][64 * 64];
    __shared__ __align__(16) short Vs[2][64 * 64];
    __shared__ short Ps[8][16 * LP];
    __shared__ __align__(16) short mfs[128];

    const int tid  = threadIdx.x;
    const int wave = tid >> 6;          // 0..7
    const int lane = tid & 63;
    const int quad = lane >> 4;
    const int l16  = lane & 15;

    const int x   = blockIdx.x;                 // 512 blocks
    const int bhh = (x & 7) + ((x >> 7) << 3);  // 4 heads per XCD (R10 swizzle)
    const int qt  = (x >> 3) & 15;
    const int b   = bhh >> 4;
    const int h   = bhh & 15;

    // each wave owns 16 Q-rows
    fragb qf0, qf1;
    {
        int qrow = qt * 128 + wave * 16 + l16;
        const short* qptr = Qb + ((size_t)bhh * Sn + qrow) * DKn + quad * 8;
        qf0 = *(const fragb*)(qptr);
        qf1 = *(const fragb*)(qptr + 32);
    }

    f4 ctx[4];
    #pragma unroll
    for (int dt = 0; dt < 4; dt++) {
        ctx[dt][0] = 0.f; ctx[dt][1] = 0.f;
        ctx[dt][2] = 0.f; ctx[dt][3] = 0.f;
    }
    f4 lacc;
    lacc[0] = 0.f; lacc[1] = 0.f; lacc[2] = 0.f; lacc[3] = 0.f;

    // staging: wave>>2 = which 64-key tile, wave&3 = which 16-row slab
    const int rw = wave & 3;
    const int hw = wave >> 2;
    const int lr = lane >> 3;
    const int sc = ((lane & 7) ^ lr) * 8;
    const short* Kg = Kb  + (size_t)bhh * Sn * DKn;
    const short* Vg = Vtb + (size_t)bhh * DKn * Sn;
    const short* mg = mfb + (size_t)b * Sn;

    const short* Ksrc = Kg + (size_t)(rw * 16 + lr) * DKn + sc;
    const short* Vsrc = Vg + (size_t)(rw * 16 + lr) * Sn + sc;

    const int c0 = ((quad ^ (l16 & 7)) * 8);

    for (int r = 0; r < 16; r++) {
        __syncthreads();
        // stage K/V tiles kt = 2r + hw (each wave: 4 GLOADs, one 16-row slab)
        const size_t kt = 2 * r + hw;
        GLOAD(Ksrc + kt * 4096,           &Ks[hw][(rw * 16) * 64]);
        GLOAD(Ksrc + kt * 4096 + 8 * DKn, &Ks[hw][(rw * 16 + 8) * 64]);
        GLOAD(Vsrc + kt * 64,             &Vs[hw][(rw * 16) * 64]);
        GLOAD(Vsrc + kt * 64 + 8 * Sn,    &Vs[hw][(rw * 16 + 8) * 64]);
        if (tid < 16)
            *(uint4*)&mfs[tid * 8] = *(const uint4*)(mg + r * 128 + tid * 8);
        __syncthreads();

        #pragma unroll
        for (int hs = 0; hs < 2; hs++) {
            #pragma unroll
            for (int t = 0; t < 4; t++) {
                fragb k0 = *(const fragb*)&Ks[hs][(t * 16 + l16) * 64 + c0];
                fragb k1 = *(const fragb*)&Ks[hs][(t * 16 + l16) * 64 + (c0 ^ 32)];
                f4 a; a[0] = 0.f; a[1] = 0.f; a[2] = 0.f; a[3] = 0.f;
                __builtin_amdgcn_s_setprio(1);
                a = __builtin_amdgcn_mfma_f32_16x16x32_bf16(k0, qf0, a, 0, 0, 0);
                a = __builtin_amdgcn_mfma_f32_16x16x32_bf16(k1, qf1, a, 0, 0, 0);
                __builtin_amdgcn_s_setprio(0);
                // raw v_exp_f32 (log2e folded into Q): 1 instr vs OCML's ~8
                unsigned u0 = __float_as_uint(__builtin_amdgcn_exp2f(a[0]));
                unsigned u1 = __float_as_uint(__builtin_amdgcn_exp2f(a[1]));
                unsigned u2 = __float_as_uint(__builtin_amdgcn_exp2f(a[2]));
                unsigned u3 = __float_as_uint(__builtin_amdgcn_exp2f(a[3]));
                uint2 pw;
                pw.x = __builtin_amdgcn_perm(u1, u0, 0x07060302u);
                pw.y = __builtin_amdgcn_perm(u3, u2, 0x07060302u);
                *(uint2*)&Ps[wave][l16 * LP + 16 * t + quad * 4] = pw;
            }

            fragb p0 = *(const fragb*)&Ps[wave][l16 * LP + quad * 8];
            fragb p1 = *(const fragb*)&Ps[wave][l16 * LP + quad * 8 + 32];
            fragb m0 = *(const fragb*)&mfs[hs * 64 + quad * 8];
            fragb m1 = *(const fragb*)&mfs[hs * 64 + quad * 8 + 32];
            __builtin_amdgcn_s_setprio(1);
            lacc = __builtin_amdgcn_mfma_f32_16x16x32_bf16(p0, m0, lacc, 0, 0, 0);
            lacc = __builtin_amdgcn_mfma_f32_16x16x32_bf16(p1, m1, lacc, 0, 0, 0);
            #pragma unroll
            for (int dt = 0; dt < 4; dt++) {
                fragb v0 = *(const fragb*)&Vs[hs][(dt * 16 + l16) * 64 + c0];
                fragb v1 = *(const fragb*)&Vs[hs][(dt * 16 + l16) * 64 + (c0 ^ 32)];
                ctx[dt] = __builtin_amdgcn_mfma_f32_16x16x32_bf16(p0, v0, ctx[dt], 0, 0, 0);
                ctx[dt] = __builtin_amdgcn_mfma_f32_16x16x32_bf16(p1, v1, ctx[dt], 0, 0, 0);
            }
            __builtin_amdgcn_s_setprio(0);
        }
    }

    // normalize in-register (lacc[r] = row's denom, same in all 16 lanes)
    #pragma unroll
    for (int r = 0; r < 4; r++) {
        int row = qt * 128 + wave * 16 + quad * 4 + r;
        float inv = 1.f / lacc[r];
        #pragma unroll
        for (int dt = 0; dt < 4; dt++)
            Ch[((size_t)(b * Sn + row)) * Dn + h * DKn + dt * 16 + l16] =
                f2h(ctx[dt][r] * inv);
    }
}

// ---------------- launch ----------------
extern "C" void kernel_launch(void* const* d_in, const int* in_sizes, int n_in,
                              void* d_out, int out_size, void* d_ws, size_t ws_size,
                              hipStream_t stream) {
    const float* x    = (const float*)d_in[0];
    const int*   mask = (const int*)d_in[1];
    const float* Wq   = (const float*)d_in[2];
    const float* bq   = (const float*)d_in[3];
    const float* Wk   = (const float*)d_in[4];
    const float* bk   = (const float*)d_in[5];
    const float* Wv   = (const float*)d_in[6];
    const float* bv   = (const float*)d_in[7];
    const float* Wo   = (const float*)d_in[8];
    const float* bo   = (const float*)d_in[9];
    float* out = (float*)d_out;

    char* ws = (char*)d_ws;
    const size_t MB = 1024u * 1024u;
    short* xh    = (short*)(ws + 0 * MB);    // 8 MB fp16 (dead after QKV)
    short* Wqh   = (short*)(ws + 8 * MB);
    short* Wkh   = (short*)(ws + 10 * MB);
    short* Wvh   = (short*)(ws + 12 * MB);
    short* Qb    = (short*)(ws + 16 * MB);
    short* Kb    = (short*)(ws + 24 * MB);
    short* Vtb   = (short*)(ws + 32 * MB);
    short* Woh   = (short*)(ws + 56 * MB);
    short* mfb   = (short*)(ws + 59 * MB);
    short* Ch    = (short*)(ws + 60 * MB);

    const int PRE = NF4 + (Bn * Sn) / 4;
    prep<<<(PRE + 255) / 256, 256, 0, stream>>>(
        x, Wq, Wk, Wv, Wo, mask, xh, Wqh, Wkh, Wvh, Woh, mfb);

    gemm_qkv<<<dim3(24, 32), 256, 0, stream>>>(
        xh, Wqh, bq, Wkh, bk, Wvh, bv, mask, Qb, Kb, Vtb);

    attn_mfma<<<dim3(Bn * Hn * (Sn / 128)), 512, 0, stream>>>(
        Qb, Kb, Vtb, mfb, Ch);

    gemm_out<<<dim3(8, 64), 256, 0, stream>>>(Ch, Woh, bo, out);
}